// Round 16
// baseline (92.173 us; speedup 1.0000x reference)
//
#include <hip/hip_runtime.h>
#include <hip/hip_bf16.h>

#define BN_EPS 1e-5f

typedef _Float16 half8 __attribute__((ext_vector_type(8)));
typedef _Float16 half4v __attribute__((ext_vector_type(4)));
typedef float f32x4v  __attribute__((ext_vector_type(4)));

static __device__ __forceinline__ float fmul(float a, float b){ return __fmul_rn(a,b); }
static __device__ __forceinline__ float fadd(float a, float b){ return __fadd_rn(a,b); }

// BN-stat accumulator banks: producers atomicAdd into bank (blockIdx & NB-1),
// consumers sum the banks in their prologue.
// layout (floats): s0[16*128] q0[16*128] s1[16*128] q1[16*128] s2[8*256] q2[8*256] = 12288
#define NB0 16
#define NB1 16
#define NB2 8

// ---------------- K0: prep — ypt tiles + weight converts + wcq/stats + xyzw build ----------------
// blocks [0,256): ypt tiles (dense W0*feat, reads pts/xyz/w0 directly; LDS-staged);
// 256: w1 convert; 257-258: w2 convert; 259: wcq + zero stats; [260,276): xyzw build
// (xyzw[pt] = {x,y,z,|p|^2} — sq computed with the EXACT op order ball query uses).
__global__ __launch_bounds__(256) void prep_kernel(const float* __restrict__ xyz,
                                                   const float* __restrict__ pts,
                                                   const float* __restrict__ w0,
                                                   const float* __restrict__ w1,
                                                   const float* __restrict__ w2,
                                                   const float* __restrict__ b0,
                                                   _Float16* __restrict__ ypt,
                                                   _Float16* __restrict__ w1h,
                                                   _Float16* __restrict__ w2h,
                                                   float4* __restrict__ wcq,
                                                   float4* __restrict__ xyzw,
                                                   float* __restrict__ stats)
{
    __shared__ half8 FL[578];      // 64 rows x 9 chunks; [576] = zero row
    __shared__ half8 WfL[1024];    // weight frags k 0..63
    __shared__ half8 W2L[136];     // xyz-slice weight frags (+zero row per tile)

    const int t = threadIdx.x;
    const unsigned bid = blockIdx.x;

    if (bid < 256) {                                   // ---- ypt tile ----
        const int p0 = bid * 64;
        const int lane = t & 63, wv = t >> 6;
        const int wr = wv >> 1, wc = wv & 1;
        const int lm = lane & 15, lg = lane >> 4;
        const int i2 = (lg == 0) ? lm : 16;

        // weight fragments from w0 (row-major [128][67], cols 3..66)
        for (int idx = t; idx < 1024; idx += 256) {
            int rg = idx >> 7, rem = idx & 127;
            int kk = rem >> 6, l = rem & 63;
            int row = rg*16 + (l & 15);
            int k0  = kk*32 + ((l >> 4) << 3);
            half8 v;
            #pragma unroll
            for (int e = 0; e < 8; ++e)
                v[e] = (_Float16)w0[row*67 + k0 + e + 3];
            WfL[idx] = v;
        }
        for (int idx = t; idx < 128; idx += 256) {
            int tile = idx >> 4, l = idx & 15;
            half8 v = {};
            v[0] = (_Float16)w0[idx*67 + 0];
            v[1] = (_Float16)w0[idx*67 + 1];
            v[2] = (_Float16)w0[idx*67 + 2];
            W2L[tile*17 + l] = v;
        }
        if (t < 8) { half8 z = {}; W2L[t*17 + 16] = z; }

        // feature tile: 64 pts x 8 chunks from pts (fp32->fp16), + abs-xyz chunk
        for (int idx = t; idx < 512; idx += 256) {
            int pt = idx >> 3, grp = idx & 7;
            const float4* p4 = (const float4*)(pts + (size_t)(p0 + pt)*64 + grp*8);
            float4 a = p4[0], b4 = p4[1];
            half8 v;
            v[0]=(_Float16)a.x;  v[1]=(_Float16)a.y;  v[2]=(_Float16)a.z;  v[3]=(_Float16)a.w;
            v[4]=(_Float16)b4.x; v[5]=(_Float16)b4.y; v[6]=(_Float16)b4.z; v[7]=(_Float16)b4.w;
            FL[pt*9 + grp] = v;
        }
        if (t < 64) {
            const float* xg = xyz + (size_t)(p0 + t)*3;
            half8 v = {};
            v[0]=(_Float16)xg[0]; v[1]=(_Float16)xg[1]; v[2]=(_Float16)xg[2];
            FL[t*9 + 8] = v;
        }
        if (t == 64) { half8 z = {}; FL[576] = z; }
        __syncthreads();

        f32x4v acc[2][4];
        #pragma unroll
        for (int pi = 0; pi < 2; ++pi)
            #pragma unroll
            for (int ci = 0; ci < 4; ++ci)
                #pragma unroll
                for (int j = 0; j < 4; ++j) acc[pi][ci][j] = 0.f;

        #pragma unroll
        for (int kk = 0; kk < 2; ++kk) {
            half8 pf[2], wf[4];
            #pragma unroll
            for (int pi = 0; pi < 2; ++pi) pf[pi] = FL[(wr*32 + pi*16 + lm)*9 + kk*4 + lg];
            #pragma unroll
            for (int ci = 0; ci < 4; ++ci) wf[ci] = WfL[(4*wc + ci)*128 + kk*64 + lane];
            #pragma unroll
            for (int pi = 0; pi < 2; ++pi)
                #pragma unroll
                for (int ci = 0; ci < 4; ++ci)
                    acc[pi][ci] = __builtin_amdgcn_mfma_f32_16x16x32_f16(pf[pi], wf[ci], acc[pi][ci], 0, 0, 0);
        }
        {   // abs-xyz slice; lg>0 lanes read zero rows on both operands
            half8 pf[2], wf[4];
            #pragma unroll
            for (int pi = 0; pi < 2; ++pi)
                pf[pi] = FL[(lg == 0) ? ((wr*32 + pi*16 + lm)*9 + 8) : 576];
            #pragma unroll
            for (int ci = 0; ci < 4; ++ci) wf[ci] = W2L[(4*wc + ci)*17 + i2];
            #pragma unroll
            for (int pi = 0; pi < 2; ++pi)
                #pragma unroll
                for (int ci = 0; ci < 4; ++ci)
                    acc[pi][ci] = __builtin_amdgcn_mfma_f32_16x16x32_f16(pf[pi], wf[ci], acc[pi][ci], 0, 0, 0);
        }

        #pragma unroll
        for (int pi = 0; pi < 2; ++pi) {
            #pragma unroll
            for (int j = 0; j < 4; ++j) {
                int n = p0 + wr*32 + pi*16 + lg*4 + j;
                size_t basep = (size_t)n * 128;
                #pragma unroll
                for (int ci = 0; ci < 4; ++ci)
                    ypt[basep + wc*64 + ci*16 + lm] = (_Float16)acc[pi][ci][j];
            }
        }
        return;
    }
    if (bid < 260) {                                   // ---- converters / init ----
        int wb = bid - 256;
        if (wb == 0) {
            for (int i = t; i < 4096; i += 256) {       // w1: 16384 floats
                float4 v = ((const float4*)w1)[i];
                half4v h;
                h[0]=(_Float16)v.x; h[1]=(_Float16)v.y; h[2]=(_Float16)v.z; h[3]=(_Float16)v.w;
                ((half4v*)w1h)[i] = h;
            }
        } else if (wb <= 2) {
            int i0 = (wb - 1) * 4096;
            for (int i = t; i < 4096; i += 256) {       // w2: 32768 floats, 2 blocks
                float4 v = ((const float4*)w2)[i0 + i];
                half4v h;
                h[0]=(_Float16)v.x; h[1]=(_Float16)v.y; h[2]=(_Float16)v.z; h[3]=(_Float16)v.w;
                ((half4v*)w2h)[i0 + i] = h;
            }
        } else {
            // wcq: per-channel {Wxyz fp16-rounded (matches MFMA weights), b0} + zero stats
            for (int idx = t; idx < 128; idx += 256) {
                _Float16 h0 = (_Float16)w0[idx*67 + 0];
                _Float16 h1 = (_Float16)w0[idx*67 + 1];
                _Float16 h2 = (_Float16)w0[idx*67 + 2];
                wcq[idx] = make_float4((float)h0, (float)h1, (float)h2, b0[idx]);
            }
            for (int i = t; i < 12288; i += 256) stats[i] = 0.f;
        }
        return;
    }
    // ---- xyzw build: 16 blocks x 1024 pts ----
    {
        const int p0 = (bid - 260) * 1024;
        for (int k = 0; k < 4; ++k) {
            int pt = p0 + k*256 + t;
            const float* xp = xyz + (size_t)pt * 3;
            float x = xp[0], y = xp[1], z = xp[2];
            float sq = fadd(fadd(fmul(x,x), fmul(y,y)), fmul(z,z));   // exact bq op order
            xyzw[pt] = make_float4(x, y, z, sq);
        }
    }
}

// ---------------- K1: FUSED ball-query + gather-pool-stats + xyz->out copy ----------------
// blocks [0,4096): 4 waves, 4 queries (one per wave). PARALLEL-SCAN/MERGE structure:
// each wave scans a FIXED quarter of the batch (1024 pts, 16 rows) and computes
// ballot masks for ALL 4 block queries from the same loaded registers — 64
// independent ballots/wave, no cnt in their dataflow, no early-exit variance ->
// full ILP, UNIFORM block durations (tail blocks no longer serialize a 4096-pt
// scan: worst-case critical path /4). Masks go to LDS; one barrier; wave w merges
// query w: the 64 saved masks in global row order with the exact per-row cnt<32
// gate, bit-test, popcll, fst latch, tail-fill -> selection byte-identical to the
// sequential scan. Phase 2 (pool) per wave's q: value = Ypt[idx[s]][c] + c_q[c];
// maxpool + analytic BN stats. blocks [4096,4144): xyz->out copy.
__global__ __launch_bounds__(256) void bqpool_kernel(const float4* __restrict__ xyzw,
                                                     const _Float16* __restrict__ ypt,
                                                     const float4* __restrict__ wcq,
                                                     const float* __restrict__ xyz,
                                                     float* __restrict__ s0a,
                                                     float* __restrict__ q0a,
                                                     _Float16* __restrict__ xm,
                                                     float* __restrict__ outbase)
{
    __shared__ unsigned long long mks[4][64];   // [query][row] ballot masks, 2KB
    __shared__ int   idxs[4][32];
    __shared__ float psh[2][4][128];

    const int t = threadIdx.x;
    const unsigned bid = blockIdx.x;
    if (bid >= 4096) {                                 // xyz -> out (new_xyz), 12288 float4
        int i = (bid - 4096) * 256 + t;
        ((float4*)outbase)[i] = ((const float4*)xyz)[i];
        return;
    }
    const int lane = t & 63;
    const int wv   = t >> 6;
    const int q0 = bid * 4;                            // block's 4 queries (one per wave)
    const int b  = q0 >> 12;
    const float4* xw = xyzw + (size_t)b * 4096;

    float4 qf[4];
    #pragma unroll
    for (int e = 0; e < 4; ++e) qf[e] = xw[(q0 + e) & 4095];

    // ---- phase 1a: each wave scans its quarter, ballots for all 4 queries ----
    {
        float4 rv[16];
        #pragma unroll
        for (int i = 0; i < 16; ++i) rv[i] = xw[wv*1024 + i*64 + lane];
        #pragma unroll
        for (int i = 0; i < 16; ++i) {
            const float4 mf = rv[i];
            #pragma unroll
            for (int e = 0; e < 4; ++e) {
                const float ee = fadd(fadd(fmul(qf[e].x,mf.x), fmul(qf[e].y,mf.y)), fmul(qf[e].z,mf.z));
                const float d  = __fsub_rn(fadd(qf[e].w, mf.w), fmul(2.0f, ee));
                unsigned long long mk = __ballot(!(d > 0.04f));   // ref: d > R^2 -> excluded
                if (lane == 0) mks[e][wv*16 + i] = mk;
            }
        }
    }
    __syncthreads();        // all waves' masks visible (uniform work -> cheap barrier)

    // ---- phase 1b: wave wv merges query wv (global row order, exact gates) ----
    int cnt = 0;
    int fst = -1;
    const unsigned long long lmask = (1ull << lane) - 1ull;
    for (int r = 0; r < 64; ++r) {
        if (cnt < 32) {                                // wave-uniform gate (overscan inert)
            const unsigned long long mask = mks[wv][r];
            if ((mask >> lane) & 1ull) {
                int pos = cnt + __popcll(mask & lmask);
                if (pos < 32) idxs[wv][pos] = r*64 + lane;
            }
            if (fst < 0 && mask) fst = r*64 + __ffsll((unsigned long long)mask) - 1;
            cnt += __popcll(mask);
        }
    }
    if (cnt < 32) {
        int slot = cnt + lane;
        if (slot < 32) idxs[wv][slot] = fst;
    }
    // idxs row is wave-local from here on: no extra barrier before phase 2

    // ---- phase 2: pool + stats for this wave's q ----
    const int li = lane & 31, hw = lane >> 5;
    const half4v* Y4 = (const half4v*)ypt;
    const float4 wq0 = wcq[li*4+0], wq1 = wcq[li*4+1], wq2 = wcq[li*4+2], wq3 = wcq[li*4+3];
    const int rbase = (q0 >> 12) << 12;
    const int q = q0 + wv;
    const float x0 = qf[wv].x, x1 = qf[wv].y, x2 = qf[wv].z;   // == xyz[q] exactly
    float cc[4];
    cc[0] = wq0.w - (wq0.x*x0 + wq0.y*x1 + wq0.z*x2);
    cc[1] = wq1.w - (wq1.x*x0 + wq1.y*x1 + wq1.z*x2);
    cc[2] = wq2.w - (wq2.x*x0 + wq2.y*x1 + wq2.z*x2);
    cc[3] = wq3.w - (wq3.x*x0 + wq3.y*x1 + wq3.z*x2);

    float m[4]  = {-3.4e38f,-3.4e38f,-3.4e38f,-3.4e38f};
    float sy[4] = {0.f,0.f,0.f,0.f};
    float yy[4] = {0.f,0.f,0.f,0.f};
    #pragma unroll
    for (int i = 0; i < 16; ++i) {
        int g = idxs[wv][2*i + hw];                   // uniform per half-wave: LDS broadcast
        half4v h = Y4[(size_t)(rbase + g)*32 + li];
        #pragma unroll
        for (int k = 0; k < 4; ++k) {
            float y = (float)h[k];
            m[k]  = fmaxf(m[k], y);
            sy[k] += y;
            yy[k] = fmaf(y, y, yy[k]);
        }
    }
    #pragma unroll
    for (int k = 0; k < 4; ++k) {
        m[k]   = fmaxf(m[k], __shfl_xor(m[k], 32));
        sy[k] += __shfl_xor(sy[k], 32);
        yy[k] += __shfl_xor(yy[k], 32);
    }
    if (hw == 0) {
        half4v ov;
        ov[0] = (_Float16)(m[0] + cc[0]);
        ov[1] = (_Float16)(m[1] + cc[1]);
        ov[2] = (_Float16)(m[2] + cc[2]);
        ov[3] = (_Float16)(m[3] + cc[3]);
        ((half4v*)xm)[(size_t)q*32 + li] = ov;
        #pragma unroll
        for (int k = 0; k < 4; ++k) {
            psh[0][wv][li*4 + k] = sy[k] + 32.f*cc[k];
            psh[1][wv][li*4 + k] = yy[k] + 2.f*cc[k]*sy[k] + 32.f*cc[k]*cc[k];
        }
    }
    __syncthreads();
    if (t < 128) {
        const int bank = bid & (NB0 - 1);
        float s  = psh[0][0][t] + psh[0][1][t] + psh[0][2][t] + psh[0][3][t];
        float qv = psh[1][0][t] + psh[1][1][t] + psh[1][2][t] + psh[1][3][t];
        atomicAdd(&s0a[bank*128 + t], s);
        atomicAdd(&q0a[bank*128 + t], qv);
    }
}

// ---------------- conv1/conv2 fp16 MFMA, position-major fp16 IO, BN(in)+ReLU fused ----------------
template<int OC, int NBOUT>
__global__ __launch_bounds__(256) void conv12_mfma_kernel(
    const _Float16* __restrict__ x, const _Float16* __restrict__ wh, const float* __restrict__ bias,
    const float* __restrict__ inS, const float* __restrict__ inQ,
    const float* __restrict__ gamma, const float* __restrict__ beta, float invc,
    _Float16* __restrict__ y, float* __restrict__ outS, float* __restrict__ outQ)
{
    __shared__ half8 Wf[8][4][64];            // 32KB
    __shared__ half8 Xf[4][4][64];            // 16KB
    __shared__ float scs[128], shs[128];
    __shared__ float psh[2][2][2][64];

    const int t = threadIdx.x, lane = t & 63, wv = t >> 6;
    const int wr = wv >> 1, wc = wv & 1;
    const int lm = lane & 15, lg = lane >> 4;
    const int n0 = blockIdx.x * 64;
    const int rb = blockIdx.y * 128;
    const int b  = blockIdx.z;

    if (t < 128) {                      // finalize input-layer BN from banked sums
        float s = 0.f, q = 0.f;
        #pragma unroll
        for (int k = 0; k < NB0; ++k) { s += inS[k*128 + t]; q += inQ[k*128 + t]; }
        float m = s * invc;
        float v = q * invc - m*m;
        float scale = gamma[t] * rsqrtf(v + BN_EPS);
        scs[t] = scale;
        shs[t] = beta[t] - m * scale;
    }
    __syncthreads();

    for (int idx = t; idx < 8*4*64; idx += 256) {
        int rg = idx >> 8, rem = idx & 255;
        int kk = rem >> 6, l = rem & 63;
        int row = rb + rg*16 + (l & 15);
        int k0  = kk*32 + (l >> 4)*8;
        Wf[rg][kk][l] = *(const half8*)(wh + row*128 + k0);
    }
    for (int idx = t; idx < 4*4*64; idx += 256) {
        int ng = idx >> 8, rem = idx & 255;
        int kk = rem >> 6, l = rem & 63;
        int n  = n0 + ng*16 + (l & 15);
        int c0 = kk*32 + (l >> 4)*8;
        half8 xv = *(const half8*)(x + (((size_t)((b << 12) + n)) << 7) + c0);
        half8 v;
        #pragma unroll
        for (int e = 0; e < 8; ++e)
            v[e] = (_Float16)fmaxf(fmaf((float)xv[e], scs[c0+e], shs[c0+e]), 0.f);
        Xf[ng][kk][l] = v;
    }
    __syncthreads();

    f32x4v acc[2][4];
    #pragma unroll
    for (int ci = 0; ci < 4; ++ci) {
        float bvv = bias[rb + wc*64 + ci*16 + lm];
        #pragma unroll
        for (int pi = 0; pi < 2; ++pi)
            #pragma unroll
            for (int j = 0; j < 4; ++j) acc[pi][ci][j] = bvv;
    }
    #pragma unroll
    for (int kk = 0; kk < 4; ++kk) {
        half8 pf[2], wf[4];
        #pragma unroll
        for (int pi = 0; pi < 2; ++pi) pf[pi] = Xf[2*wr + pi][kk][lane];
        #pragma unroll
        for (int ci = 0; ci < 4; ++ci) wf[ci] = Wf[4*wc + ci][kk][lane];
        #pragma unroll
        for (int pi = 0; pi < 2; ++pi)
            #pragma unroll
            for (int ci = 0; ci < 4; ++ci)
                acc[pi][ci] = __builtin_amdgcn_mfma_f32_16x16x32_f16(pf[pi], wf[ci], acc[pi][ci], 0, 0, 0);
    }

    float ssum[4], ssq[4];
    #pragma unroll
    for (int ci = 0; ci < 4; ++ci) { ssum[ci] = 0.f; ssq[ci] = 0.f; }
    #pragma unroll
    for (int pi = 0; pi < 2; ++pi) {
        #pragma unroll
        for (int j = 0; j < 4; ++j) {
            int n = n0 + wr*32 + pi*16 + lg*4 + j;
            size_t basep = (size_t)((b << 12) + n) * OC + rb;
            #pragma unroll
            for (int ci = 0; ci < 4; ++ci) {
                float v = acc[pi][ci][j];
                y[basep + wc*64 + ci*16 + lm] = (_Float16)v;
                ssum[ci] += v;
                ssq[ci]  = fmaf(v, v, ssq[ci]);
            }
        }
    }
    #pragma unroll
    for (int ci = 0; ci < 4; ++ci) {
        float s  = ssum[ci], s2 = ssq[ci];
        s  += __shfl_xor(s, 16);  s  += __shfl_xor(s, 32);
        s2 += __shfl_xor(s2, 16); s2 += __shfl_xor(s2, 32);
        if (lg == 0) {
            psh[0][wr][wc][ci*16 + lm] = s;
            psh[1][wr][wc][ci*16 + lm] = s2;
        }
    }
    __syncthreads();
    if (t < 128) {
        const int bank = (blockIdx.x + blockIdx.y + (blockIdx.z << 2)) & (NBOUT - 1);
        atomicAdd(&outS[(size_t)bank*OC + rb + t], psh[0][0][t >> 6][t & 63] + psh[0][1][t >> 6][t & 63]);
        atomicAdd(&outQ[(size_t)bank*OC + rb + t], psh[1][0][t >> 6][t & 63] + psh[1][1][t >> 6][t & 63]);
    }
}

// ---------------- final: BN2 finalize (from banked sums) + ReLU on y2h -> out fp32 ----------------
__global__ __launch_bounds__(256) void final_apply_kernel(const _Float16* __restrict__ y2h,
                                                          const float* __restrict__ s2a,
                                                          const float* __restrict__ q2a,
                                                          const float* __restrict__ gamma,
                                                          const float* __restrict__ beta,
                                                          float invc,
                                                          float* __restrict__ outbase)
{
    __shared__ float scs[256], shs[256];
    const int t = threadIdx.x;
    {
        float s = 0.f, q = 0.f;
        #pragma unroll
        for (int k = 0; k < NB2; ++k) { s += s2a[k*256 + t]; q += q2a[k*256 + t]; }
        float m = s * invc;
        float v = q * invc - m*m;
        float scale = gamma[t] * rsqrtf(v + BN_EPS);
        scs[t] = scale;
        shs[t] = beta[t] - m * scale;
    }
    __syncthreads();
    int i = blockIdx.x * 256 + t;                  // half8 index, [0, 524288)
    half8 v = ((const half8*)y2h)[i];
    int c0 = (i & 31) * 8;
    float4 o0, o1;
    o0.x = fmaxf(fmaf((float)v[0], scs[c0+0], shs[c0+0]), 0.f);
    o0.y = fmaxf(fmaf((float)v[1], scs[c0+1], shs[c0+1]), 0.f);
    o0.z = fmaxf(fmaf((float)v[2], scs[c0+2], shs[c0+2]), 0.f);
    o0.w = fmaxf(fmaf((float)v[3], scs[c0+3], shs[c0+3]), 0.f);
    o1.x = fmaxf(fmaf((float)v[4], scs[c0+4], shs[c0+4]), 0.f);
    o1.y = fmaxf(fmaf((float)v[5], scs[c0+5], shs[c0+5]), 0.f);
    o1.z = fmaxf(fmaf((float)v[6], scs[c0+6], shs[c0+6]), 0.f);
    o1.w = fmaxf(fmaf((float)v[7], scs[c0+7], shs[c0+7]), 0.f);
    float4* op = (float4*)(outbase + 49152);
    op[2*i]   = o0;
    op[2*i+1] = o1;
}

extern "C" void kernel_launch(void* const* d_in, const int* in_sizes, int n_in,
                              void* d_out, int out_size, void* d_ws, size_t ws_size,
                              hipStream_t stream)
{
    const float* xyz = (const float*)d_in[0];
    const float* pts = (const float*)d_in[1];
    const float* w0  = (const float*)d_in[2];
    const float* b0  = (const float*)d_in[3];
    const float* g0  = (const float*)d_in[4];
    const float* bt0 = (const float*)d_in[5];
    const float* w1  = (const float*)d_in[6];
    const float* b1  = (const float*)d_in[7];
    const float* g1  = (const float*)d_in[8];
    const float* bt1 = (const float*)d_in[9];
    const float* w2  = (const float*)d_in[10];
    const float* b2  = (const float*)d_in[11];
    const float* g2  = (const float*)d_in[12];
    const float* bt2 = (const float*)d_in[13];
    float* out = (float*)d_out;

    // Layout: xyzw [2M,+256K) xm [4.5M,8.5M) y1 [8.5M,12.5M) y2 [12.5M,20.5M)
    //         stats [20.5M,+48K) W [24M,+164K) ypt @32M (dedicated, no aliasing)
    char* ws = (char*)d_ws;
    float4*   xyzw = (float4*)(ws + 2097152);
    _Float16* xmh  = (_Float16*)(ws + 4718592);
    _Float16* y1h  = (_Float16*)(ws + 8912896);
    _Float16* y2h  = (_Float16*)(ws + 13107200);
    float*    stb  = (float*)(ws + 21495808);        // 12288-float banked BN-stat block
    float *s0a = stb,        *q0a = stb + 2048;      // 16 banks x 128, layer0 count 524288
    float *s1a = stb + 4096, *q1a = stb + 6144;      // 16 banks x 128, layer1 count 16384
    float *s2a = stb + 8192, *q2a = stb + 10240;     // 8 banks x 256, layer2 count 16384
    char*     wb   = ws + (24u << 20);
    float4*   wcq  = (float4*)(wb + 20480);          // 2048 B
    _Float16* w1h  = (_Float16*)(wb + 32768);        // 32768 B
    _Float16* w2h  = (_Float16*)(wb + 98304);        // 65536 B
    _Float16* ypt  = (_Float16*)(ws + ((ws_size >= (38u << 20)) ? (size_t)(32u << 20)
                                                                : (size_t)13107200));

    prep_kernel<<<276, 256, 0, stream>>>(xyz, pts, w0, w1, w2, b0, ypt,
                                         w1h, w2h, wcq, xyzw, stb);
    bqpool_kernel<<<4144, 256, 0, stream>>>(xyzw, ypt, wcq, xyz, s0a, q0a, xmh, out);
    conv12_mfma_kernel<128, NB1><<<dim3(64,1,4), 256, 0, stream>>>(xmh, w1h, b1, s0a, q0a,
                                                                   g0, bt0, 1.f/524288.f,
                                                                   y1h, s1a, q1a);
    conv12_mfma_kernel<256, NB2><<<dim3(64,2,4), 256, 0, stream>>>(y1h, w2h, b2, s1a, q1a,
                                                                   g1, bt1, 1.f/16384.f,
                                                                   y2h, s2a, q2a);
    final_apply_kernel<<<2048, 256, 0, stream>>>(y2h, s2a, q2a, g2, bt2, 1.f/16384.f, out);
}

// Round 17
// 66.741 us; speedup vs baseline: 1.3811x; 1.3811x over previous
//
#include <hip/hip_runtime.h>
#include <hip/hip_bf16.h>

#define BN_EPS 1e-5f

typedef _Float16 half8 __attribute__((ext_vector_type(8)));
typedef _Float16 half4v __attribute__((ext_vector_type(4)));
typedef float f32x4v  __attribute__((ext_vector_type(4)));

static __device__ __forceinline__ float fmul(float a, float b){ return __fmul_rn(a,b); }
static __device__ __forceinline__ float fadd(float a, float b){ return __fadd_rn(a,b); }

// BN-stat accumulator banks: producers atomicAdd into bank (blockIdx & NB-1),
// consumers sum the banks in their prologue.
// layout (floats): s0[16*128] q0[16*128] s1[16*128] q1[16*128] s2[8*256] q2[8*256] = 12288
#define NB0 16
#define NB1 16
#define NB2 8

// ---------------- K0: prep — ypt tiles + weight converts + wcq/stats + xyzw build ----------------
// blocks [0,256): ypt tiles (dense W0*feat, reads pts/xyz/w0 directly; LDS-staged);
// 256: w1 convert; 257-258: w2 convert; 259: wcq + zero stats; [260,276): xyzw build
// (xyzw[pt] = {x,y,z,|p|^2} — sq computed with the EXACT op order ball query uses).
__global__ __launch_bounds__(256) void prep_kernel(const float* __restrict__ xyz,
                                                   const float* __restrict__ pts,
                                                   const float* __restrict__ w0,
                                                   const float* __restrict__ w1,
                                                   const float* __restrict__ w2,
                                                   const float* __restrict__ b0,
                                                   _Float16* __restrict__ ypt,
                                                   _Float16* __restrict__ w1h,
                                                   _Float16* __restrict__ w2h,
                                                   float4* __restrict__ wcq,
                                                   float4* __restrict__ xyzw,
                                                   float* __restrict__ stats)
{
    __shared__ half8 FL[578];      // 64 rows x 9 chunks; [576] = zero row
    __shared__ half8 WfL[1024];    // weight frags k 0..63
    __shared__ half8 W2L[136];     // xyz-slice weight frags (+zero row per tile)

    const int t = threadIdx.x;
    const unsigned bid = blockIdx.x;

    if (bid < 256) {                                   // ---- ypt tile ----
        const int p0 = bid * 64;
        const int lane = t & 63, wv = t >> 6;
        const int wr = wv >> 1, wc = wv & 1;
        const int lm = lane & 15, lg = lane >> 4;
        const int i2 = (lg == 0) ? lm : 16;

        // weight fragments from w0 (row-major [128][67], cols 3..66)
        for (int idx = t; idx < 1024; idx += 256) {
            int rg = idx >> 7, rem = idx & 127;
            int kk = rem >> 6, l = rem & 63;
            int row = rg*16 + (l & 15);
            int k0  = kk*32 + ((l >> 4) << 3);
            half8 v;
            #pragma unroll
            for (int e = 0; e < 8; ++e)
                v[e] = (_Float16)w0[row*67 + k0 + e + 3];
            WfL[idx] = v;
        }
        for (int idx = t; idx < 128; idx += 256) {
            int tile = idx >> 4, l = idx & 15;
            half8 v = {};
            v[0] = (_Float16)w0[idx*67 + 0];
            v[1] = (_Float16)w0[idx*67 + 1];
            v[2] = (_Float16)w0[idx*67 + 2];
            W2L[tile*17 + l] = v;
        }
        if (t < 8) { half8 z = {}; W2L[t*17 + 16] = z; }

        // feature tile: 64 pts x 8 chunks from pts (fp32->fp16), + abs-xyz chunk
        for (int idx = t; idx < 512; idx += 256) {
            int pt = idx >> 3, grp = idx & 7;
            const float4* p4 = (const float4*)(pts + (size_t)(p0 + pt)*64 + grp*8);
            float4 a = p4[0], b4 = p4[1];
            half8 v;
            v[0]=(_Float16)a.x;  v[1]=(_Float16)a.y;  v[2]=(_Float16)a.z;  v[3]=(_Float16)a.w;
            v[4]=(_Float16)b4.x; v[5]=(_Float16)b4.y; v[6]=(_Float16)b4.z; v[7]=(_Float16)b4.w;
            FL[pt*9 + grp] = v;
        }
        if (t < 64) {
            const float* xg = xyz + (size_t)(p0 + t)*3;
            half8 v = {};
            v[0]=(_Float16)xg[0]; v[1]=(_Float16)xg[1]; v[2]=(_Float16)xg[2];
            FL[t*9 + 8] = v;
        }
        if (t == 64) { half8 z = {}; FL[576] = z; }
        __syncthreads();

        f32x4v acc[2][4];
        #pragma unroll
        for (int pi = 0; pi < 2; ++pi)
            #pragma unroll
            for (int ci = 0; ci < 4; ++ci)
                #pragma unroll
                for (int j = 0; j < 4; ++j) acc[pi][ci][j] = 0.f;

        #pragma unroll
        for (int kk = 0; kk < 2; ++kk) {
            half8 pf[2], wf[4];
            #pragma unroll
            for (int pi = 0; pi < 2; ++pi) pf[pi] = FL[(wr*32 + pi*16 + lm)*9 + kk*4 + lg];
            #pragma unroll
            for (int ci = 0; ci < 4; ++ci) wf[ci] = WfL[(4*wc + ci)*128 + kk*64 + lane];
            #pragma unroll
            for (int pi = 0; pi < 2; ++pi)
                #pragma unroll
                for (int ci = 0; ci < 4; ++ci)
                    acc[pi][ci] = __builtin_amdgcn_mfma_f32_16x16x32_f16(pf[pi], wf[ci], acc[pi][ci], 0, 0, 0);
        }
        {   // abs-xyz slice; lg>0 lanes read zero rows on both operands
            half8 pf[2], wf[4];
            #pragma unroll
            for (int pi = 0; pi < 2; ++pi)
                pf[pi] = FL[(lg == 0) ? ((wr*32 + pi*16 + lm)*9 + 8) : 576];
            #pragma unroll
            for (int ci = 0; ci < 4; ++ci) wf[ci] = W2L[(4*wc + ci)*17 + i2];
            #pragma unroll
            for (int pi = 0; pi < 2; ++pi)
                #pragma unroll
                for (int ci = 0; ci < 4; ++ci)
                    acc[pi][ci] = __builtin_amdgcn_mfma_f32_16x16x32_f16(pf[pi], wf[ci], acc[pi][ci], 0, 0, 0);
        }

        #pragma unroll
        for (int pi = 0; pi < 2; ++pi) {
            #pragma unroll
            for (int j = 0; j < 4; ++j) {
                int n = p0 + wr*32 + pi*16 + lg*4 + j;
                size_t basep = (size_t)n * 128;
                #pragma unroll
                for (int ci = 0; ci < 4; ++ci)
                    ypt[basep + wc*64 + ci*16 + lm] = (_Float16)acc[pi][ci][j];
            }
        }
        return;
    }
    if (bid < 260) {                                   // ---- converters / init ----
        int wb = bid - 256;
        if (wb == 0) {
            for (int i = t; i < 4096; i += 256) {       // w1: 16384 floats
                float4 v = ((const float4*)w1)[i];
                half4v h;
                h[0]=(_Float16)v.x; h[1]=(_Float16)v.y; h[2]=(_Float16)v.z; h[3]=(_Float16)v.w;
                ((half4v*)w1h)[i] = h;
            }
        } else if (wb <= 2) {
            int i0 = (wb - 1) * 4096;
            for (int i = t; i < 4096; i += 256) {       // w2: 32768 floats, 2 blocks
                float4 v = ((const float4*)w2)[i0 + i];
                half4v h;
                h[0]=(_Float16)v.x; h[1]=(_Float16)v.y; h[2]=(_Float16)v.z; h[3]=(_Float16)v.w;
                ((half4v*)w2h)[i0 + i] = h;
            }
        } else {
            // wcq: per-channel {Wxyz fp16-rounded (matches MFMA weights), b0} + zero stats
            for (int idx = t; idx < 128; idx += 256) {
                _Float16 h0 = (_Float16)w0[idx*67 + 0];
                _Float16 h1 = (_Float16)w0[idx*67 + 1];
                _Float16 h2 = (_Float16)w0[idx*67 + 2];
                wcq[idx] = make_float4((float)h0, (float)h1, (float)h2, b0[idx]);
            }
            for (int i = t; i < 12288; i += 256) stats[i] = 0.f;
        }
        return;
    }
    // ---- xyzw build: 16 blocks x 1024 pts ----
    {
        const int p0 = (bid - 260) * 1024;
        for (int k = 0; k < 4; ++k) {
            int pt = p0 + k*256 + t;
            const float* xp = xyz + (size_t)pt * 3;
            float x = xp[0], y = xp[1], z = xp[2];
            float sq = fadd(fadd(fmul(x,x), fmul(y,y)), fmul(z,z));   // exact bq op order
            xyzw[pt] = make_float4(x, y, z, sq);
        }
    }
}

// ---------------- K1: FUSED ball-query + gather-pool-stats + xyz->out copy ----------------
// blocks [0,2048): 4 waves x 2 queries each (8 q/block). Round-9 skeleton (1024-pt
// chunk, 16-deep register load batch, waves fully uncoupled) + multi-query sharing
// at Q=2: each loaded batch feeds TWO independent ballot chains -> scan L2 traffic
// halved without the occupancy/ILP collapse of Q=4 (grid stays 2048x4=8192 waves).
// Per-q gating (cnt<32, wave-uniform) is the established overscan-inert condition ->
// neighbor selection bit-exact ('first' latches once). Phase 2 (pool) per q:
// value = Ypt[idx[s]][c] + c_q[c]; maxpool + analytic stats. idxs are wave-local ->
// no block barrier between phases. blocks [2048,2096): xyz->out copy.
__global__ __launch_bounds__(256) void bqpool_kernel(const float4* __restrict__ xyzw,
                                                     const _Float16* __restrict__ ypt,
                                                     const float4* __restrict__ wcq,
                                                     const float* __restrict__ xyz,
                                                     float* __restrict__ s0a,
                                                     float* __restrict__ q0a,
                                                     _Float16* __restrict__ xm,
                                                     float* __restrict__ outbase)
{
    __shared__ int   idxs[8][32];
    __shared__ float psh[2][4][128];

    const int t = threadIdx.x;
    const unsigned bid = blockIdx.x;
    if (bid >= 2048) {                                 // xyz -> out (new_xyz), 12288 float4
        int i = (bid - 2048) * 256 + t;
        ((float4*)outbase)[i] = ((const float4*)xyz)[i];
        return;
    }
    const int lane = t & 63;
    const int wv   = t >> 6;
    const int q0 = bid * 8 + wv * 2;                   // this wave's 2 queries
    const int b  = q0 >> 12;
    const float4* xw = xyzw + (size_t)b * 4096;

    float4 qf[2];
    #pragma unroll
    for (int e = 0; e < 2; ++e) qf[e] = xw[(q0 + e) & 4095];

    // ---- phase 1: 2-query chunked ball query (16-deep load batch, uncoupled) ----
    int cnt[2] = {0,0};
    int fst[2] = {-1,-1};
    for (int cb = 0; cb < 4096; cb += 1024) {
        float4 rv[16];
        #pragma unroll
        for (int i = 0; i < 16; ++i) rv[i] = xw[cb + i*64 + lane];
        #pragma unroll
        for (int i = 0; i < 16; ++i) {
            const float4 mf = rv[i];
            #pragma unroll
            for (int e = 0; e < 2; ++e) {
                if (cnt[e] < 32) {                     // wave-uniform gate (overscan inert)
                    const float ee = fadd(fadd(fmul(qf[e].x,mf.x), fmul(qf[e].y,mf.y)), fmul(qf[e].z,mf.z));
                    const float d  = __fsub_rn(fadd(qf[e].w, mf.w), fmul(2.0f, ee));
                    const bool in = !(d > 0.04f);      // ref: d > R^2 -> excluded
                    const unsigned long long mask = __ballot(in);
                    if (in) {
                        int pos = cnt[e] + __popcll(mask & ((1ull << lane) - 1ull));
                        if (pos < 32) idxs[wv*2 + e][pos] = cb + i*64 + lane;
                    }
                    if (fst[e] < 0 && mask) fst[e] = cb + i*64 + __ffsll((unsigned long long)mask) - 1;
                    cnt[e] += __popcll(mask);
                }
            }
        }
        if (cnt[0] >= 32 && cnt[1] >= 32) break;
    }
    #pragma unroll
    for (int e = 0; e < 2; ++e) {
        if (cnt[e] < 32) {
            int slot = cnt[e] + lane;
            if (slot < 32) idxs[wv*2 + e][slot] = fst[e];
        }
    }
    // idxs rows are wave-local: no block barrier needed before phase 2

    // ---- phase 2: pool + stats for this wave's 2 q's ----
    const int li = lane & 31, hw = lane >> 5;
    const half4v* Y4 = (const half4v*)ypt;
    const float4 wq0 = wcq[li*4+0], wq1 = wcq[li*4+1], wq2 = wcq[li*4+2], wq3 = wcq[li*4+3];
    const int rbase = (q0 >> 12) << 12;
    float ss[4] = {0.f,0.f,0.f,0.f}, qq[4] = {0.f,0.f,0.f,0.f};

    #pragma unroll
    for (int e = 0; e < 2; ++e) {
        const int q = q0 + e;
        const float x0 = qf[e].x, x1 = qf[e].y, x2 = qf[e].z;   // == xyz[q] exactly
        float cc[4];
        cc[0] = wq0.w - (wq0.x*x0 + wq0.y*x1 + wq0.z*x2);
        cc[1] = wq1.w - (wq1.x*x0 + wq1.y*x1 + wq1.z*x2);
        cc[2] = wq2.w - (wq2.x*x0 + wq2.y*x1 + wq2.z*x2);
        cc[3] = wq3.w - (wq3.x*x0 + wq3.y*x1 + wq3.z*x2);

        float m[4]  = {-3.4e38f,-3.4e38f,-3.4e38f,-3.4e38f};
        float sy[4] = {0.f,0.f,0.f,0.f};
        float yy[4] = {0.f,0.f,0.f,0.f};
        #pragma unroll
        for (int i = 0; i < 16; ++i) {
            int g = idxs[wv*2 + e][2*i + hw];         // uniform per half-wave: LDS broadcast
            half4v h = Y4[(size_t)(rbase + g)*32 + li];
            #pragma unroll
            for (int k = 0; k < 4; ++k) {
                float y = (float)h[k];
                m[k]  = fmaxf(m[k], y);
                sy[k] += y;
                yy[k] = fmaf(y, y, yy[k]);
            }
        }
        #pragma unroll
        for (int k = 0; k < 4; ++k) {
            m[k]   = fmaxf(m[k], __shfl_xor(m[k], 32));
            sy[k] += __shfl_xor(sy[k], 32);
            yy[k] += __shfl_xor(yy[k], 32);
        }
        if (hw == 0) {
            half4v ov;
            ov[0] = (_Float16)(m[0] + cc[0]);
            ov[1] = (_Float16)(m[1] + cc[1]);
            ov[2] = (_Float16)(m[2] + cc[2]);
            ov[3] = (_Float16)(m[3] + cc[3]);
            ((half4v*)xm)[(size_t)q*32 + li] = ov;
        }
        #pragma unroll
        for (int k = 0; k < 4; ++k) {
            ss[k] += sy[k] + 32.f*cc[k];
            qq[k] += yy[k] + 2.f*cc[k]*sy[k] + 32.f*cc[k]*cc[k];
        }
    }

    if (hw == 0) {
        #pragma unroll
        for (int k = 0; k < 4; ++k) {
            psh[0][wv][li*4 + k] = ss[k];
            psh[1][wv][li*4 + k] = qq[k];
        }
    }
    __syncthreads();
    if (t < 128) {
        const int bank = bid & (NB0 - 1);
        float s  = psh[0][0][t] + psh[0][1][t] + psh[0][2][t] + psh[0][3][t];
        float qv = psh[1][0][t] + psh[1][1][t] + psh[1][2][t] + psh[1][3][t];
        atomicAdd(&s0a[bank*128 + t], s);
        atomicAdd(&q0a[bank*128 + t], qv);
    }
}

// ---------------- conv1/conv2 fp16 MFMA, position-major fp16 IO, BN(in)+ReLU fused ----------------
template<int OC, int NBOUT>
__global__ __launch_bounds__(256) void conv12_mfma_kernel(
    const _Float16* __restrict__ x, const _Float16* __restrict__ wh, const float* __restrict__ bias,
    const float* __restrict__ inS, const float* __restrict__ inQ,
    const float* __restrict__ gamma, const float* __restrict__ beta, float invc,
    _Float16* __restrict__ y, float* __restrict__ outS, float* __restrict__ outQ)
{
    __shared__ half8 Wf[8][4][64];            // 32KB
    __shared__ half8 Xf[4][4][64];            // 16KB
    __shared__ float scs[128], shs[128];
    __shared__ float psh[2][2][2][64];

    const int t = threadIdx.x, lane = t & 63, wv = t >> 6;
    const int wr = wv >> 1, wc = wv & 1;
    const int lm = lane & 15, lg = lane >> 4;
    const int n0 = blockIdx.x * 64;
    const int rb = blockIdx.y * 128;
    const int b  = blockIdx.z;

    if (t < 128) {                      // finalize input-layer BN from banked sums
        float s = 0.f, q = 0.f;
        #pragma unroll
        for (int k = 0; k < NB0; ++k) { s += inS[k*128 + t]; q += inQ[k*128 + t]; }
        float m = s * invc;
        float v = q * invc - m*m;
        float scale = gamma[t] * rsqrtf(v + BN_EPS);
        scs[t] = scale;
        shs[t] = beta[t] - m * scale;
    }
    __syncthreads();

    for (int idx = t; idx < 8*4*64; idx += 256) {
        int rg = idx >> 8, rem = idx & 255;
        int kk = rem >> 6, l = rem & 63;
        int row = rb + rg*16 + (l & 15);
        int k0  = kk*32 + (l >> 4)*8;
        Wf[rg][kk][l] = *(const half8*)(wh + row*128 + k0);
    }
    for (int idx = t; idx < 4*4*64; idx += 256) {
        int ng = idx >> 8, rem = idx & 255;
        int kk = rem >> 6, l = rem & 63;
        int n  = n0 + ng*16 + (l & 15);
        int c0 = kk*32 + (l >> 4)*8;
        half8 xv = *(const half8*)(x + (((size_t)((b << 12) + n)) << 7) + c0);
        half8 v;
        #pragma unroll
        for (int e = 0; e < 8; ++e)
            v[e] = (_Float16)fmaxf(fmaf((float)xv[e], scs[c0+e], shs[c0+e]), 0.f);
        Xf[ng][kk][l] = v;
    }
    __syncthreads();

    f32x4v acc[2][4];
    #pragma unroll
    for (int ci = 0; ci < 4; ++ci) {
        float bvv = bias[rb + wc*64 + ci*16 + lm];
        #pragma unroll
        for (int pi = 0; pi < 2; ++pi)
            #pragma unroll
            for (int j = 0; j < 4; ++j) acc[pi][ci][j] = bvv;
    }
    #pragma unroll
    for (int kk = 0; kk < 4; ++kk) {
        half8 pf[2], wf[4];
        #pragma unroll
        for (int pi = 0; pi < 2; ++pi) pf[pi] = Xf[2*wr + pi][kk][lane];
        #pragma unroll
        for (int ci = 0; ci < 4; ++ci) wf[ci] = Wf[4*wc + ci][kk][lane];
        #pragma unroll
        for (int pi = 0; pi < 2; ++pi)
            #pragma unroll
            for (int ci = 0; ci < 4; ++ci)
                acc[pi][ci] = __builtin_amdgcn_mfma_f32_16x16x32_f16(pf[pi], wf[ci], acc[pi][ci], 0, 0, 0);
    }

    float ssum[4], ssq[4];
    #pragma unroll
    for (int ci = 0; ci < 4; ++ci) { ssum[ci] = 0.f; ssq[ci] = 0.f; }
    #pragma unroll
    for (int pi = 0; pi < 2; ++pi) {
        #pragma unroll
        for (int j = 0; j < 4; ++j) {
            int n = n0 + wr*32 + pi*16 + lg*4 + j;
            size_t basep = (size_t)((b << 12) + n) * OC + rb;
            #pragma unroll
            for (int ci = 0; ci < 4; ++ci) {
                float v = acc[pi][ci][j];
                y[basep + wc*64 + ci*16 + lm] = (_Float16)v;
                ssum[ci] += v;
                ssq[ci]  = fmaf(v, v, ssq[ci]);
            }
        }
    }
    #pragma unroll
    for (int ci = 0; ci < 4; ++ci) {
        float s  = ssum[ci], s2 = ssq[ci];
        s  += __shfl_xor(s, 16);  s  += __shfl_xor(s, 32);
        s2 += __shfl_xor(s2, 16); s2 += __shfl_xor(s2, 32);
        if (lg == 0) {
            psh[0][wr][wc][ci*16 + lm] = s;
            psh[1][wr][wc][ci*16 + lm] = s2;
        }
    }
    __syncthreads();
    if (t < 128) {
        const int bank = (blockIdx.x + blockIdx.y + (blockIdx.z << 2)) & (NBOUT - 1);
        atomicAdd(&outS[(size_t)bank*OC + rb + t], psh[0][0][t >> 6][t & 63] + psh[0][1][t >> 6][t & 63]);
        atomicAdd(&outQ[(size_t)bank*OC + rb + t], psh[1][0][t >> 6][t & 63] + psh[1][1][t >> 6][t & 63]);
    }
}

// ---------------- final: BN2 finalize (from banked sums) + ReLU on y2h -> out fp32 ----------------
__global__ __launch_bounds__(256) void final_apply_kernel(const _Float16* __restrict__ y2h,
                                                          const float* __restrict__ s2a,
                                                          const float* __restrict__ q2a,
                                                          const float* __restrict__ gamma,
                                                          const float* __restrict__ beta,
                                                          float invc,
                                                          float* __restrict__ outbase)
{
    __shared__ float scs[256], shs[256];
    const int t = threadIdx.x;
    {
        float s = 0.f, q = 0.f;
        #pragma unroll
        for (int k = 0; k < NB2; ++k) { s += s2a[k*256 + t]; q += q2a[k*256 + t]; }
        float m = s * invc;
        float v = q * invc - m*m;
        float scale = gamma[t] * rsqrtf(v + BN_EPS);
        scs[t] = scale;
        shs[t] = beta[t] - m * scale;
    }
    __syncthreads();
    int i = blockIdx.x * 256 + t;                  // half8 index, [0, 524288)
    half8 v = ((const half8*)y2h)[i];
    int c0 = (i & 31) * 8;
    float4 o0, o1;
    o0.x = fmaxf(fmaf((float)v[0], scs[c0+0], shs[c0+0]), 0.f);
    o0.y = fmaxf(fmaf((float)v[1], scs[c0+1], shs[c0+1]), 0.f);
    o0.z = fmaxf(fmaf((float)v[2], scs[c0+2], shs[c0+2]), 0.f);
    o0.w = fmaxf(fmaf((float)v[3], scs[c0+3], shs[c0+3]), 0.f);
    o1.x = fmaxf(fmaf((float)v[4], scs[c0+4], shs[c0+4]), 0.f);
    o1.y = fmaxf(fmaf((float)v[5], scs[c0+5], shs[c0+5]), 0.f);
    o1.z = fmaxf(fmaf((float)v[6], scs[c0+6], shs[c0+6]), 0.f);
    o1.w = fmaxf(fmaf((float)v[7], scs[c0+7], shs[c0+7]), 0.f);
    float4* op = (float4*)(outbase + 49152);
    op[2*i]   = o0;
    op[2*i+1] = o1;
}

extern "C" void kernel_launch(void* const* d_in, const int* in_sizes, int n_in,
                              void* d_out, int out_size, void* d_ws, size_t ws_size,
                              hipStream_t stream)
{
    const float* xyz = (const float*)d_in[0];
    const float* pts = (const float*)d_in[1];
    const float* w0  = (const float*)d_in[2];
    const float* b0  = (const float*)d_in[3];
    const float* g0  = (const float*)d_in[4];
    const float* bt0 = (const float*)d_in[5];
    const float* w1  = (const float*)d_in[6];
    const float* b1  = (const float*)d_in[7];
    const float* g1  = (const float*)d_in[8];
    const float* bt1 = (const float*)d_in[9];
    const float* w2  = (const float*)d_in[10];
    const float* b2  = (const float*)d_in[11];
    const float* g2  = (const float*)d_in[12];
    const float* bt2 = (const float*)d_in[13];
    float* out = (float*)d_out;

    // Layout: xyzw [2M,+256K) xm [4.5M,8.5M) y1 [8.5M,12.5M) y2 [12.5M,20.5M)
    //         stats [20.5M,+48K) W [24M,+164K) ypt @32M (dedicated, no aliasing)
    char* ws = (char*)d_ws;
    float4*   xyzw = (float4*)(ws + 2097152);
    _Float16* xmh  = (_Float16*)(ws + 4718592);
    _Float16* y1h  = (_Float16*)(ws + 8912896);
    _Float16* y2h  = (_Float16*)(ws + 13107200);
    float*    stb  = (float*)(ws + 21495808);        // 12288-float banked BN-stat block
    float *s0a = stb,        *q0a = stb + 2048;      // 16 banks x 128, layer0 count 524288
    float *s1a = stb + 4096, *q1a = stb + 6144;      // 16 banks x 128, layer1 count 16384
    float *s2a = stb + 8192, *q2a = stb + 10240;     // 8 banks x 256, layer2 count 16384
    char*     wb   = ws + (24u << 20);
    float4*   wcq  = (float4*)(wb + 20480);          // 2048 B
    _Float16* w1h  = (_Float16*)(wb + 32768);        // 32768 B
    _Float16* w2h  = (_Float16*)(wb + 98304);        // 65536 B
    _Float16* ypt  = (_Float16*)(ws + ((ws_size >= (38u << 20)) ? (size_t)(32u << 20)
                                                                : (size_t)13107200));

    prep_kernel<<<276, 256, 0, stream>>>(xyz, pts, w0, w1, w2, b0, ypt,
                                         w1h, w2h, wcq, xyzw, stb);
    bqpool_kernel<<<2096, 256, 0, stream>>>(xyzw, ypt, wcq, xyz, s0a, q0a, xmh, out);
    conv12_mfma_kernel<128, NB1><<<dim3(64,1,4), 256, 0, stream>>>(xmh, w1h, b1, s0a, q0a,
                                                                   g0, bt0, 1.f/524288.f,
                                                                   y1h, s1a, q1a);
    conv12_mfma_kernel<256, NB2><<<dim3(64,2,4), 256, 0, stream>>>(y1h, w2h, b2, s1a, q1a,
                                                                   g1, bt1, 1.f/16384.f,
                                                                   y2h, s2a, q2a);
    final_apply_kernel<<<2048, 256, 0, stream>>>(y2h, s2a, q2a, g2, bt2, 1.f/16384.f, out);
}

// Round 18
// 63.393 us; speedup vs baseline: 1.4540x; 1.0528x over previous
//
#include <hip/hip_runtime.h>
#include <hip/hip_bf16.h>

#define BN_EPS 1e-5f

typedef _Float16 half8 __attribute__((ext_vector_type(8)));
typedef _Float16 half4v __attribute__((ext_vector_type(4)));
typedef float f32x4v  __attribute__((ext_vector_type(4)));

static __device__ __forceinline__ float fmul(float a, float b){ return __fmul_rn(a,b); }
static __device__ __forceinline__ float fadd(float a, float b){ return __fadd_rn(a,b); }

// BN-stat accumulator banks: producers atomicAdd into bank (blockIdx & NB-1),
// consumers sum the banks in their prologue.
// layout (floats): s0[16*128] q0[16*128] s1[16*128] q1[16*128] s2[8*256] q2[8*256] = 12288
#define NB0 16
#define NB1 16
#define NB2 8

// ---------------- K0: prep — ypt tiles + weight converts + wcq/stats + xyzw build ----------------
// blocks [0,256): ypt tiles (dense W0*feat, reads pts/xyz/w0 directly; LDS-staged);
// 256: w1 convert; 257-258: w2 convert; 259: wcq + zero stats; [260,276): xyzw build
// (xyzw[pt] = {x,y,z,|p|^2} — sq computed with the EXACT op order ball query uses).
__global__ __launch_bounds__(256) void prep_kernel(const float* __restrict__ xyz,
                                                   const float* __restrict__ pts,
                                                   const float* __restrict__ w0,
                                                   const float* __restrict__ w1,
                                                   const float* __restrict__ w2,
                                                   const float* __restrict__ b0,
                                                   _Float16* __restrict__ ypt,
                                                   _Float16* __restrict__ w1h,
                                                   _Float16* __restrict__ w2h,
                                                   float4* __restrict__ wcq,
                                                   float4* __restrict__ xyzw,
                                                   float* __restrict__ stats)
{
    __shared__ half8 FL[578];      // 64 rows x 9 chunks; [576] = zero row
    __shared__ half8 WfL[1024];    // weight frags k 0..63
    __shared__ half8 W2L[136];     // xyz-slice weight frags (+zero row per tile)

    const int t = threadIdx.x;
    const unsigned bid = blockIdx.x;

    if (bid < 256) {                                   // ---- ypt tile ----
        const int p0 = bid * 64;
        const int lane = t & 63, wv = t >> 6;
        const int wr = wv >> 1, wc = wv & 1;
        const int lm = lane & 15, lg = lane >> 4;
        const int i2 = (lg == 0) ? lm : 16;

        // weight fragments from w0 (row-major [128][67], cols 3..66)
        for (int idx = t; idx < 1024; idx += 256) {
            int rg = idx >> 7, rem = idx & 127;
            int kk = rem >> 6, l = rem & 63;
            int row = rg*16 + (l & 15);
            int k0  = kk*32 + ((l >> 4) << 3);
            half8 v;
            #pragma unroll
            for (int e = 0; e < 8; ++e)
                v[e] = (_Float16)w0[row*67 + k0 + e + 3];
            WfL[idx] = v;
        }
        for (int idx = t; idx < 128; idx += 256) {
            int tile = idx >> 4, l = idx & 15;
            half8 v = {};
            v[0] = (_Float16)w0[idx*67 + 0];
            v[1] = (_Float16)w0[idx*67 + 1];
            v[2] = (_Float16)w0[idx*67 + 2];
            W2L[tile*17 + l] = v;
        }
        if (t < 8) { half8 z = {}; W2L[t*17 + 16] = z; }

        // feature tile: 64 pts x 8 chunks from pts (fp32->fp16), + abs-xyz chunk
        for (int idx = t; idx < 512; idx += 256) {
            int pt = idx >> 3, grp = idx & 7;
            const float4* p4 = (const float4*)(pts + (size_t)(p0 + pt)*64 + grp*8);
            float4 a = p4[0], b4 = p4[1];
            half8 v;
            v[0]=(_Float16)a.x;  v[1]=(_Float16)a.y;  v[2]=(_Float16)a.z;  v[3]=(_Float16)a.w;
            v[4]=(_Float16)b4.x; v[5]=(_Float16)b4.y; v[6]=(_Float16)b4.z; v[7]=(_Float16)b4.w;
            FL[pt*9 + grp] = v;
        }
        if (t < 64) {
            const float* xg = xyz + (size_t)(p0 + t)*3;
            half8 v = {};
            v[0]=(_Float16)xg[0]; v[1]=(_Float16)xg[1]; v[2]=(_Float16)xg[2];
            FL[t*9 + 8] = v;
        }
        if (t == 64) { half8 z = {}; FL[576] = z; }
        __syncthreads();

        f32x4v acc[2][4];
        #pragma unroll
        for (int pi = 0; pi < 2; ++pi)
            #pragma unroll
            for (int ci = 0; ci < 4; ++ci)
                #pragma unroll
                for (int j = 0; j < 4; ++j) acc[pi][ci][j] = 0.f;

        #pragma unroll
        for (int kk = 0; kk < 2; ++kk) {
            half8 pf[2], wf[4];
            #pragma unroll
            for (int pi = 0; pi < 2; ++pi) pf[pi] = FL[(wr*32 + pi*16 + lm)*9 + kk*4 + lg];
            #pragma unroll
            for (int ci = 0; ci < 4; ++ci) wf[ci] = WfL[(4*wc + ci)*128 + kk*64 + lane];
            #pragma unroll
            for (int pi = 0; pi < 2; ++pi)
                #pragma unroll
                for (int ci = 0; ci < 4; ++ci)
                    acc[pi][ci] = __builtin_amdgcn_mfma_f32_16x16x32_f16(pf[pi], wf[ci], acc[pi][ci], 0, 0, 0);
        }
        {   // abs-xyz slice; lg>0 lanes read zero rows on both operands
            half8 pf[2], wf[4];
            #pragma unroll
            for (int pi = 0; pi < 2; ++pi)
                pf[pi] = FL[(lg == 0) ? ((wr*32 + pi*16 + lm)*9 + 8) : 576];
            #pragma unroll
            for (int ci = 0; ci < 4; ++ci) wf[ci] = W2L[(4*wc + ci)*17 + i2];
            #pragma unroll
            for (int pi = 0; pi < 2; ++pi)
                #pragma unroll
                for (int ci = 0; ci < 4; ++ci)
                    acc[pi][ci] = __builtin_amdgcn_mfma_f32_16x16x32_f16(pf[pi], wf[ci], acc[pi][ci], 0, 0, 0);
        }

        #pragma unroll
        for (int pi = 0; pi < 2; ++pi) {
            #pragma unroll
            for (int j = 0; j < 4; ++j) {
                int n = p0 + wr*32 + pi*16 + lg*4 + j;
                size_t basep = (size_t)n * 128;
                #pragma unroll
                for (int ci = 0; ci < 4; ++ci)
                    ypt[basep + wc*64 + ci*16 + lm] = (_Float16)acc[pi][ci][j];
            }
        }
        return;
    }
    if (bid < 260) {                                   // ---- converters / init ----
        int wb = bid - 256;
        if (wb == 0) {
            for (int i = t; i < 4096; i += 256) {       // w1: 16384 floats
                float4 v = ((const float4*)w1)[i];
                half4v h;
                h[0]=(_Float16)v.x; h[1]=(_Float16)v.y; h[2]=(_Float16)v.z; h[3]=(_Float16)v.w;
                ((half4v*)w1h)[i] = h;
            }
        } else if (wb <= 2) {
            int i0 = (wb - 1) * 4096;
            for (int i = t; i < 4096; i += 256) {       // w2: 32768 floats, 2 blocks
                float4 v = ((const float4*)w2)[i0 + i];
                half4v h;
                h[0]=(_Float16)v.x; h[1]=(_Float16)v.y; h[2]=(_Float16)v.z; h[3]=(_Float16)v.w;
                ((half4v*)w2h)[i0 + i] = h;
            }
        } else {
            // wcq: per-channel {Wxyz fp16-rounded (matches MFMA weights), b0} + zero stats
            for (int idx = t; idx < 128; idx += 256) {
                _Float16 h0 = (_Float16)w0[idx*67 + 0];
                _Float16 h1 = (_Float16)w0[idx*67 + 1];
                _Float16 h2 = (_Float16)w0[idx*67 + 2];
                wcq[idx] = make_float4((float)h0, (float)h1, (float)h2, b0[idx]);
            }
            for (int i = t; i < 12288; i += 256) stats[i] = 0.f;
        }
        return;
    }
    // ---- xyzw build: 16 blocks x 1024 pts ----
    {
        const int p0 = (bid - 260) * 1024;
        for (int k = 0; k < 4; ++k) {
            int pt = p0 + k*256 + t;
            const float* xp = xyz + (size_t)pt * 3;
            float x = xp[0], y = xp[1], z = xp[2];
            float sq = fadd(fadd(fmul(x,x), fmul(y,y)), fmul(z,z));   // exact bq op order
            xyzw[pt] = make_float4(x, y, z, sq);
        }
    }
}

// ---------------- K1: FUSED ball-query + gather-pool-stats + xyz->out copy ----------------
// blocks [0,2048): 4 waves x 2 queries each (8 q/block). Round-12 proven skeleton
// (1024-pt chunk, 16-deep register load batch, waves fully uncoupled, Q=2 sharing).
// Per-q gating (cnt<32, wave-uniform) is the established overscan-inert condition ->
// neighbor selection bit-exact. NEW vs round 12: the per-row `fst` (first-neighbor)
// tracking is deleted from the hot loop — it is provably redundant: tail-fill only
// runs when cnt<32, i.e. the gate stayed open through the WHOLE scan, so every
// in-radius point was recorded and the first one is idxs[e][0] (first pass got
// pos=0; cnt>=1 always since the query itself has d=0<=R^2). Tail-fill reads
// idxs[e][0] (wave-lockstep: broadcast read precedes fills; fill slots start at
// cnt>=1 so [0] is never clobbered first). Output bit-identical, ~5 fewer ops and
// one less loop-carried dependency per row-instance.
// Phase 2 (pool) per q: value = Ypt[idx[s]][c] + c_q[c]; maxpool + analytic stats.
// idxs are wave-local -> no block barrier between phases. blocks [2048,2096): copy.
__global__ __launch_bounds__(256) void bqpool_kernel(const float4* __restrict__ xyzw,
                                                     const _Float16* __restrict__ ypt,
                                                     const float4* __restrict__ wcq,
                                                     const float* __restrict__ xyz,
                                                     float* __restrict__ s0a,
                                                     float* __restrict__ q0a,
                                                     _Float16* __restrict__ xm,
                                                     float* __restrict__ outbase)
{
    __shared__ int   idxs[8][32];
    __shared__ float psh[2][4][128];

    const int t = threadIdx.x;
    const unsigned bid = blockIdx.x;
    if (bid >= 2048) {                                 // xyz -> out (new_xyz), 12288 float4
        int i = (bid - 2048) * 256 + t;
        ((float4*)outbase)[i] = ((const float4*)xyz)[i];
        return;
    }
    const int lane = t & 63;
    const int wv   = t >> 6;
    const int q0 = bid * 8 + wv * 2;                   // this wave's 2 queries
    const int b  = q0 >> 12;
    const float4* xw = xyzw + (size_t)b * 4096;

    float4 qf[2];
    #pragma unroll
    for (int e = 0; e < 2; ++e) qf[e] = xw[(q0 + e) & 4095];

    // ---- phase 1: 2-query chunked ball query (16-deep load batch, uncoupled) ----
    int cnt[2] = {0,0};
    for (int cb = 0; cb < 4096; cb += 1024) {
        float4 rv[16];
        #pragma unroll
        for (int i = 0; i < 16; ++i) rv[i] = xw[cb + i*64 + lane];
        #pragma unroll
        for (int i = 0; i < 16; ++i) {
            const float4 mf = rv[i];
            #pragma unroll
            for (int e = 0; e < 2; ++e) {
                if (cnt[e] < 32) {                     // wave-uniform gate (overscan inert)
                    const float ee = fadd(fadd(fmul(qf[e].x,mf.x), fmul(qf[e].y,mf.y)), fmul(qf[e].z,mf.z));
                    const float d  = __fsub_rn(fadd(qf[e].w, mf.w), fmul(2.0f, ee));
                    const bool in = !(d > 0.04f);      // ref: d > R^2 -> excluded
                    const unsigned long long mask = __ballot(in);
                    if (in) {
                        int pos = cnt[e] + __popcll(mask & ((1ull << lane) - 1ull));
                        if (pos < 32) idxs[wv*2 + e][pos] = cb + i*64 + lane;
                    }
                    cnt[e] += __popcll(mask);
                }
            }
        }
        if (cnt[0] >= 32 && cnt[1] >= 32) break;
    }
    #pragma unroll
    for (int e = 0; e < 2; ++e) {
        if (cnt[e] < 32) {
            // gate stayed open all scan -> idxs[..][0] = lowest-index in-radius point
            // (cnt >= 1 guaranteed: the query point itself has d = 0 <= R^2)
            int f = idxs[wv*2 + e][0];
            int slot = cnt[e] + lane;                  // slot >= 1, never overwrites [0] first
            if (slot < 32) idxs[wv*2 + e][slot] = f;
        }
    }
    // idxs rows are wave-local: no block barrier needed before phase 2

    // ---- phase 2: pool + stats for this wave's 2 q's ----
    const int li = lane & 31, hw = lane >> 5;
    const half4v* Y4 = (const half4v*)ypt;
    const float4 wq0 = wcq[li*4+0], wq1 = wcq[li*4+1], wq2 = wcq[li*4+2], wq3 = wcq[li*4+3];
    const int rbase = (q0 >> 12) << 12;
    float ss[4] = {0.f,0.f,0.f,0.f}, qq[4] = {0.f,0.f,0.f,0.f};

    #pragma unroll
    for (int e = 0; e < 2; ++e) {
        const int q = q0 + e;
        const float x0 = qf[e].x, x1 = qf[e].y, x2 = qf[e].z;   // == xyz[q] exactly
        float cc[4];
        cc[0] = wq0.w - (wq0.x*x0 + wq0.y*x1 + wq0.z*x2);
        cc[1] = wq1.w - (wq1.x*x0 + wq1.y*x1 + wq1.z*x2);
        cc[2] = wq2.w - (wq2.x*x0 + wq2.y*x1 + wq2.z*x2);
        cc[3] = wq3.w - (wq3.x*x0 + wq3.y*x1 + wq3.z*x2);

        float m[4]  = {-3.4e38f,-3.4e38f,-3.4e38f,-3.4e38f};
        float sy[4] = {0.f,0.f,0.f,0.f};
        float yy[4] = {0.f,0.f,0.f,0.f};
        #pragma unroll
        for (int i = 0; i < 16; ++i) {
            int g = idxs[wv*2 + e][2*i + hw];         // uniform per half-wave: LDS broadcast
            half4v h = Y4[(size_t)(rbase + g)*32 + li];
            #pragma unroll
            for (int k = 0; k < 4; ++k) {
                float y = (float)h[k];
                m[k]  = fmaxf(m[k], y);
                sy[k] += y;
                yy[k] = fmaf(y, y, yy[k]);
            }
        }
        #pragma unroll
        for (int k = 0; k < 4; ++k) {
            m[k]   = fmaxf(m[k], __shfl_xor(m[k], 32));
            sy[k] += __shfl_xor(sy[k], 32);
            yy[k] += __shfl_xor(yy[k], 32);
        }
        if (hw == 0) {
            half4v ov;
            ov[0] = (_Float16)(m[0] + cc[0]);
            ov[1] = (_Float16)(m[1] + cc[1]);
            ov[2] = (_Float16)(m[2] + cc[2]);
            ov[3] = (_Float16)(m[3] + cc[3]);
            ((half4v*)xm)[(size_t)q*32 + li] = ov;
        }
        #pragma unroll
        for (int k = 0; k < 4; ++k) {
            ss[k] += sy[k] + 32.f*cc[k];
            qq[k] += yy[k] + 2.f*cc[k]*sy[k] + 32.f*cc[k]*cc[k];
        }
    }

    if (hw == 0) {
        #pragma unroll
        for (int k = 0; k < 4; ++k) {
            psh[0][wv][li*4 + k] = ss[k];
            psh[1][wv][li*4 + k] = qq[k];
        }
    }
    __syncthreads();
    if (t < 128) {
        const int bank = bid & (NB0 - 1);
        float s  = psh[0][0][t] + psh[0][1][t] + psh[0][2][t] + psh[0][3][t];
        float qv = psh[1][0][t] + psh[1][1][t] + psh[1][2][t] + psh[1][3][t];
        atomicAdd(&s0a[bank*128 + t], s);
        atomicAdd(&q0a[bank*128 + t], qv);
    }
}

// ---------------- conv1/conv2 fp16 MFMA, position-major fp16 IO, BN(in)+ReLU fused ----------------
template<int OC, int NBOUT>
__global__ __launch_bounds__(256) void conv12_mfma_kernel(
    const _Float16* __restrict__ x, const _Float16* __restrict__ wh, const float* __restrict__ bias,
    const float* __restrict__ inS, const float* __restrict__ inQ,
    const float* __restrict__ gamma, const float* __restrict__ beta, float invc,
    _Float16* __restrict__ y, float* __restrict__ outS, float* __restrict__ outQ)
{
    __shared__ half8 Wf[8][4][64];            // 32KB
    __shared__ half8 Xf[4][4][64];            // 16KB
    __shared__ float scs[128], shs[128];
    __shared__ float psh[2][2][2][64];

    const int t = threadIdx.x, lane = t & 63, wv = t >> 6;
    const int wr = wv >> 1, wc = wv & 1;
    const int lm = lane & 15, lg = lane >> 4;
    const int n0 = blockIdx.x * 64;
    const int rb = blockIdx.y * 128;
    const int b  = blockIdx.z;

    if (t < 128) {                      // finalize input-layer BN from banked sums
        float s = 0.f, q = 0.f;
        #pragma unroll
        for (int k = 0; k < NB0; ++k) { s += inS[k*128 + t]; q += inQ[k*128 + t]; }
        float m = s * invc;
        float v = q * invc - m*m;
        float scale = gamma[t] * rsqrtf(v + BN_EPS);
        scs[t] = scale;
        shs[t] = beta[t] - m * scale;
    }
    __syncthreads();

    for (int idx = t; idx < 8*4*64; idx += 256) {
        int rg = idx >> 8, rem = idx & 255;
        int kk = rem >> 6, l = rem & 63;
        int row = rb + rg*16 + (l & 15);
        int k0  = kk*32 + (l >> 4)*8;
        Wf[rg][kk][l] = *(const half8*)(wh + row*128 + k0);
    }
    for (int idx = t; idx < 4*4*64; idx += 256) {
        int ng = idx >> 8, rem = idx & 255;
        int kk = rem >> 6, l = rem & 63;
        int n  = n0 + ng*16 + (l & 15);
        int c0 = kk*32 + (l >> 4)*8;
        half8 xv = *(const half8*)(x + (((size_t)((b << 12) + n)) << 7) + c0);
        half8 v;
        #pragma unroll
        for (int e = 0; e < 8; ++e)
            v[e] = (_Float16)fmaxf(fmaf((float)xv[e], scs[c0+e], shs[c0+e]), 0.f);
        Xf[ng][kk][l] = v;
    }
    __syncthreads();

    f32x4v acc[2][4];
    #pragma unroll
    for (int ci = 0; ci < 4; ++ci) {
        float bvv = bias[rb + wc*64 + ci*16 + lm];
        #pragma unroll
        for (int pi = 0; pi < 2; ++pi)
            #pragma unroll
            for (int j = 0; j < 4; ++j) acc[pi][ci][j] = bvv;
    }
    #pragma unroll
    for (int kk = 0; kk < 4; ++kk) {
        half8 pf[2], wf[4];
        #pragma unroll
        for (int pi = 0; pi < 2; ++pi) pf[pi] = Xf[2*wr + pi][kk][lane];
        #pragma unroll
        for (int ci = 0; ci < 4; ++ci) wf[ci] = Wf[4*wc + ci][kk][lane];
        #pragma unroll
        for (int pi = 0; pi < 2; ++pi)
            #pragma unroll
            for (int ci = 0; ci < 4; ++ci)
                acc[pi][ci] = __builtin_amdgcn_mfma_f32_16x16x32_f16(pf[pi], wf[ci], acc[pi][ci], 0, 0, 0);
    }

    float ssum[4], ssq[4];
    #pragma unroll
    for (int ci = 0; ci < 4; ++ci) { ssum[ci] = 0.f; ssq[ci] = 0.f; }
    #pragma unroll
    for (int pi = 0; pi < 2; ++pi) {
        #pragma unroll
        for (int j = 0; j < 4; ++j) {
            int n = n0 + wr*32 + pi*16 + lg*4 + j;
            size_t basep = (size_t)((b << 12) + n) * OC + rb;
            #pragma unroll
            for (int ci = 0; ci < 4; ++ci) {
                float v = acc[pi][ci][j];
                y[basep + wc*64 + ci*16 + lm] = (_Float16)v;
                ssum[ci] += v;
                ssq[ci]  = fmaf(v, v, ssq[ci]);
            }
        }
    }
    #pragma unroll
    for (int ci = 0; ci < 4; ++ci) {
        float s  = ssum[ci], s2 = ssq[ci];
        s  += __shfl_xor(s, 16);  s  += __shfl_xor(s, 32);
        s2 += __shfl_xor(s2, 16); s2 += __shfl_xor(s2, 32);
        if (lg == 0) {
            psh[0][wr][wc][ci*16 + lm] = s;
            psh[1][wr][wc][ci*16 + lm] = s2;
        }
    }
    __syncthreads();
    if (t < 128) {
        const int bank = (blockIdx.x + blockIdx.y + (blockIdx.z << 2)) & (NBOUT - 1);
        atomicAdd(&outS[(size_t)bank*OC + rb + t], psh[0][0][t >> 6][t & 63] + psh[0][1][t >> 6][t & 63]);
        atomicAdd(&outQ[(size_t)bank*OC + rb + t], psh[1][0][t >> 6][t & 63] + psh[1][1][t >> 6][t & 63]);
    }
}

// ---------------- final: BN2 finalize (from banked sums) + ReLU on y2h -> out fp32 ----------------
__global__ __launch_bounds__(256) void final_apply_kernel(const _Float16* __restrict__ y2h,
                                                          const float* __restrict__ s2a,
                                                          const float* __restrict__ q2a,
                                                          const float* __restrict__ gamma,
                                                          const float* __restrict__ beta,
                                                          float invc,
                                                          float* __restrict__ outbase)
{
    __shared__ float scs[256], shs[256];
    const int t = threadIdx.x;
    {
        float s = 0.f, q = 0.f;
        #pragma unroll
        for (int k = 0; k < NB2; ++k) { s += s2a[k*256 + t]; q += q2a[k*256 + t]; }
        float m = s * invc;
        float v = q * invc - m*m;
        float scale = gamma[t] * rsqrtf(v + BN_EPS);
        scs[t] = scale;
        shs[t] = beta[t] - m * scale;
    }
    __syncthreads();
    int i = blockIdx.x * 256 + t;                  // half8 index, [0, 524288)
    half8 v = ((const half8*)y2h)[i];
    int c0 = (i & 31) * 8;
    float4 o0, o1;
    o0.x = fmaxf(fmaf((float)v[0], scs[c0+0], shs[c0+0]), 0.f);
    o0.y = fmaxf(fmaf((float)v[1], scs[c0+1], shs[c0+1]), 0.f);
    o0.z = fmaxf(fmaf((float)v[2], scs[c0+2], shs[c0+2]), 0.f);
    o0.w = fmaxf(fmaf((float)v[3], scs[c0+3], shs[c0+3]), 0.f);
    o1.x = fmaxf(fmaf((float)v[4], scs[c0+4], shs[c0+4]), 0.f);
    o1.y = fmaxf(fmaf((float)v[5], scs[c0+5], shs[c0+5]), 0.f);
    o1.z = fmaxf(fmaf((float)v[6], scs[c0+6], shs[c0+6]), 0.f);
    o1.w = fmaxf(fmaf((float)v[7], scs[c0+7], shs[c0+7]), 0.f);
    float4* op = (float4*)(outbase + 49152);
    op[2*i]   = o0;
    op[2*i+1] = o1;
}

extern "C" void kernel_launch(void* const* d_in, const int* in_sizes, int n_in,
                              void* d_out, int out_size, void* d_ws, size_t ws_size,
                              hipStream_t stream)
{
    const float* xyz = (const float*)d_in[0];
    const float* pts = (const float*)d_in[1];
    const float* w0  = (const float*)d_in[2];
    const float* b0  = (const float*)d_in[3];
    const float* g0  = (const float*)d_in[4];
    const float* bt0 = (const float*)d_in[5];
    const float* w1  = (const float*)d_in[6];
    const float* b1  = (const float*)d_in[7];
    const float* g1  = (const float*)d_in[8];
    const float* bt1 = (const float*)d_in[9];
    const float* w2  = (const float*)d_in[10];
    const float* b2  = (const float*)d_in[11];
    const float* g2  = (const float*)d_in[12];
    const float* bt2 = (const float*)d_in[13];
    float* out = (float*)d_out;

    // Layout: xyzw [2M,+256K) xm [4.5M,8.5M) y1 [8.5M,12.5M) y2 [12.5M,20.5M)
    //         stats [20.5M,+48K) W [24M,+164K) ypt @32M (dedicated, no aliasing)
    char* ws = (char*)d_ws;
    float4*   xyzw = (float4*)(ws + 2097152);
    _Float16* xmh  = (_Float16*)(ws + 4718592);
    _Float16* y1h  = (_Float16*)(ws + 8912896);
    _Float16* y2h  = (_Float16*)(ws + 13107200);
    float*    stb  = (float*)(ws + 21495808);        // 12288-float banked BN-stat block
    float *s0a = stb,        *q0a = stb + 2048;      // 16 banks x 128, layer0 count 524288
    float *s1a = stb + 4096, *q1a = stb + 6144;      // 16 banks x 128, layer1 count 16384
    float *s2a = stb + 8192, *q2a = stb + 10240;     // 8 banks x 256, layer2 count 16384
    char*     wb   = ws + (24u << 20);
    float4*   wcq  = (float4*)(wb + 20480);          // 2048 B
    _Float16* w1h  = (_Float16*)(wb + 32768);        // 32768 B
    _Float16* w2h  = (_Float16*)(wb + 98304);        // 65536 B
    _Float16* ypt  = (_Float16*)(ws + ((ws_size >= (38u << 20)) ? (size_t)(32u << 20)
                                                                : (size_t)13107200));

    prep_kernel<<<276, 256, 0, stream>>>(xyz, pts, w0, w1, w2, b0, ypt,
                                         w1h, w2h, wcq, xyzw, stb);
    bqpool_kernel<<<2096, 256, 0, stream>>>(xyzw, ypt, wcq, xyz, s0a, q0a, xmh, out);
    conv12_mfma_kernel<128, NB1><<<dim3(64,1,4), 256, 0, stream>>>(xmh, w1h, b1, s0a, q0a,
                                                                   g0, bt0, 1.f/524288.f,
                                                                   y1h, s1a, q1a);
    conv12_mfma_kernel<256, NB2><<<dim3(64,2,4), 256, 0, stream>>>(y1h, w2h, b2, s1a, q1a,
                                                                   g1, bt1, 1.f/16384.f,
                                                                   y2h, s2a, q2a);
    final_apply_kernel<<<2048, 256, 0, stream>>>(y2h, s2a, q2a, g2, bt2, 1.f/16384.f, out);
}